// Round 12
// baseline (168.765 us; speedup 1.0000x reference)
//
#include <hip/hip_runtime.h>

// ConvertParamsTEtoParams0TEGaussLayer — MFMA v4: zero-LDS Newton + 4-wave blocks.
// 256-thread blocks = 4 independent waves; each wave owns 4 batches (no
// barriers, waves never interact). Single-wave blocks capped occupancy at
// 16 blocks/CU (workgroup-slot limit); 4-wave blocks reach 32 waves/CU.
//
// Fragment algebra (lane t = 16h + c, h=t>>4, c=t&15):
//   D-frag  reg j = D[4h+j][c]
//   B-frag  reg i = B[4h+i][c]   => B-frag(X) = cvt4(X-as-D)   (always)
//   A-frag  reg i = A[c][4h+i]   => A-frag(X^T) = cvt4(X-as-D) (always)
//                                  A-frag(X)  = cvt4(X-as-D) iff X symmetric
// Inverses by Newton iteration on the matrix pipe:
//   Pinv:  X0 = 0.7*I; X <- X(2I - P X), 5 steps (rho(I-0.7P) <= ~0.3).
//   cinv:  L = I+N nilpotent: X1 = 2I-L, 3 steps exact; maintain X and X^T.
// Chain: symS = S+S^T; M1 = Pinv@Hv; G = symS@M1; U' = Pinv@G; Z = HvT^T@M1;
// ZT = M1^T@HvT; V2 = Hv^T@U'; am = V2-Z-ZT; T1T = MF(cvt4(am), cinvA);
// arg = MF(cvt4(T1T), cinvA); phi-mask; cam = La@arg; out = LvT@La + Lv@cam.

typedef _Float16 f16x4 __attribute__((ext_vector_type(4)));
typedef float    f32x4 __attribute__((ext_vector_type(4)));

__device__ __forceinline__ unsigned int pkf(float a, float b) {
  return __builtin_bit_cast(unsigned int, __builtin_amdgcn_cvt_pkrtz(a, b));
}
__device__ __forceinline__ f16x4 mkf16x4(unsigned int lo, unsigned int hi) {
  union { unsigned int u[2]; f16x4 v; } cv; cv.u[0] = lo; cv.u[1] = hi; return cv.v;
}
__device__ __forceinline__ f16x4 cvt4(f32x4 d) {
  return mkf16x4(pkf(d[0], d[1]), pkf(d[2], d[3]));
}
__device__ __forceinline__ f16x4 cvt4f(float a, float b, float c, float d) {
  return mkf16x4(pkf(a, b), pkf(c, d));
}
__device__ __forceinline__ f32x4 MF(f16x4 a, f16x4 b, f32x4 c) {
  return __builtin_amdgcn_mfma_f32_16x16x16f16(a, b, c, 0, 0, 0);
}
// A-frag from global (row pattern): X[r][4h..4h+3]; also = B-frag(X^T).
__device__ __forceinline__ f16x4 ldA(const float* __restrict__ X, int r, int h) {
  float4 v = *reinterpret_cast<const float4*>(X + r * 16 + 4 * h);
  return cvt4f(v.x, v.y, v.z, v.w);
}
// B-frag from global (column pattern): X[4h+i][c]; also = A-frag(X^T).
__device__ __forceinline__ f16x4 ldBcol(const float* __restrict__ X, int h, int c) {
  const float* b = X + 4 * h * 16 + c;
  return cvt4f(b[0], b[16], b[32], b[48]);
}

__global__ __launch_bounds__(256, 8) void gauss_te_mf4(
    const float* __restrict__ mu_TE,
    const float* __restrict__ prec_h,
    const float* __restrict__ chol_v,
    const float* __restrict__ chol_h,
    const float* __restrict__ chol_hv,
    const float* __restrict__ chol_v_TE,
    const float* __restrict__ chol_h_TE,
    const float* __restrict__ chol_hv_TE,
    const float* __restrict__ chol_amat,
    float* __restrict__ out, int B)
{
  const int wv = threadIdx.x >> 6;      // wave in block (0..3), independent
  const int t = threadIdx.x & 63;       // lane in wave
  const int g = t >> 4;                 // h-role (row block)
  const int l = t & 15;                 // c-role (column)
  const size_t batch0 = ((size_t)blockIdx.x * 4 + wv) * 4;
  const f32x4 zz = {0.f, 0.f, 0.f, 0.f};

  // ---- muv_TE passthrough (one batch per 16-lane group) ----
  out[(size_t)B * 256 + (batch0 + g) * 16 + l] = mu_TE[(batch0 + g) * 32 + l];

  size_t off[4];
  #pragma unroll
  for (int b = 0; b < 4; ++b) off[b] = (batch0 + b) * 256;

  // ---- symS = S + S^T, S = LhT@Lh^T + HvT@Hv^T (symmetric -> one frag) ----
  f16x4 syh[4];
  #pragma unroll
  for (int b = 0; b < 4; ++b) {
    f16x4 lhtA = ldA(chol_h_TE  + off[b], l, g);  // A-frag(LhT)
    f16x4 lhB  = ldA(chol_h     + off[b], l, g);  // B-frag(Lh^T)
    f16x4 hvtA = ldA(chol_hv_TE + off[b], l, g);  // A-frag(HvT)
    f16x4 hvA  = ldA(chol_hv    + off[b], l, g);  // B-frag(Hv^T)
    f32x4 S  = MF(lhtA, lhB, zz);                 // LhT @ Lh^T
    S        = MF(hvtA, hvA, S);                  // + HvT @ Hv^T
    f32x4 St = MF(lhB, lhtA, zz);                 // Lh @ LhT^T  (= S^T)
    St       = MF(hvA, hvtA, St);                 // + Hv @ HvT^T
    syh[b] = cvt4(S + St);
  }

  // ---- Pinv by Newton (5 steps), all-MFMA, symmetric iterates ----
  f16x4 pinvF[4];
  {
    f16x4 Pf[4];
    f32x4 X[4];
    #pragma unroll
    for (int b = 0; b < 4; ++b) {
      Pf[b] = ldA(prec_h + off[b], l, g);         // A-frag(P) (symmetric)
      #pragma unroll
      for (int j = 0; j < 4; ++j) X[b][j] = (4 * g + j == l) ? 0.7f : 0.f;
    }
    #pragma unroll
    for (int s = 0; s < 5; ++s) {
      #pragma unroll
      for (int b = 0; b < 4; ++b) {
        f16x4 xh = cvt4(X[b]);                    // A- and B-frag of X (sym)
        f32x4 Y  = MF(Pf[b], xh, zz);             // Y = P@X
        f32x4 XY = MF(xh, cvt4(Y), zz);           // X@Y
        X[b] = 2.0f * X[b] - XY;
      }
    }
    #pragma unroll
    for (int b = 0; b < 4; ++b) pinvF[b] = cvt4(X[b]);
  }

  // ---- cinv by Newton (exact after 3 steps), maintain X and X^T ----
  f16x4 laA[4], cinvA[4];
  {
    f32x4 X[4], XT[4];
    #pragma unroll
    for (int b = 0; b < 4; ++b) {
      const float* base = chol_amat + off[b];
      const float4 rv = *reinterpret_cast<const float4*>(base + l * 16 + 4 * g);
      laA[b] = cvt4f(rv.x, rv.y, rv.z, rv.w);     // A-frag(La)
      const float rr[4] = {rv.x, rv.y, rv.z, rv.w};
      const float* cb = base + 4 * g * 16 + l;    // column l of La
      #pragma unroll
      for (int j = 0; j < 4; ++j) {
        const float d = (4 * g + j == l) ? 2.f : 0.f;
        X[b][j]  = d - cb[16 * j];                // X1   = 2I - La
        XT[b][j] = d - rr[j];                     // X1^T = 2I - La^T
      }
    }
    #pragma unroll
    for (int s = 0; s < 3; ++s) {
      #pragma unroll
      for (int b = 0; b < 4; ++b) {
        f16x4 xh  = cvt4(X[b]);                   // B-frag(X)
        f16x4 xth = cvt4(XT[b]);                  // A-frag(X) = B-frag(X^T)
        f32x4 Y   = MF(laA[b], xh, zz);           // Y = La@X
        f16x4 yh  = cvt4(Y);
        f32x4 XY  = MF(xth, yh, zz);              // X@Y
        f32x4 YT  = MF(yh, xth, zz);              // Y^T@X^T = (X@Y)^T
        X[b]  = 2.f * X[b]  - XY;
        XT[b] = 2.f * XT[b] - YT;
      }
    }
    #pragma unroll
    for (int b = 0; b < 4; ++b) cinvA[b] = cvt4(XT[b]);  // A-frag(cinv) = B-frag(cinv^T)
  }

  // ---- main chain, 4 independent batch chains ----
  #pragma unroll
  for (int b = 0; b < 4; ++b) {
    f16x4 hvB  = ldBcol(chol_hv    + off[b], g, l);  // B-frag(Hv) = A-frag(Hv^T)
    f16x4 hvtB = ldBcol(chol_hv_TE + off[b], g, l);  // B-frag(HvT) = A-frag(HvT^T)
    f32x4 M1 = MF(pinvF[b], hvB, zz);             // M1 = Pinv@Hv
    f16x4 m1h = cvt4(M1);
    f32x4 G  = MF(syh[b], m1h, zz);               // G = symS@M1 (symS as A)
    f32x4 Up = MF(pinvF[b], cvt4(G), zz);         // U' = Pinv@G = (W+W^T)@Hv
    f32x4 Z  = MF(hvtB, m1h, zz);                 // Z   = HvT^T@M1
    f32x4 ZT = MF(m1h, hvtB, zz);                 // Z^T = M1^T@HvT
    f32x4 V2 = MF(hvB, cvt4(Up), zz);             // V2' = Hv^T@U'
    f32x4 am = V2 - Z - ZT;                       // amatTE (D-layout)
    f32x4 T1T = MF(cvt4(am), cinvA[b], zz);       // (cinv@am)^T = am^T@cinv^T
    f32x4 arg = MF(cvt4(T1T), cinvA[b], zz);      // arg = cinv@am@cinv^T
    #pragma unroll
    for (int j = 0; j < 4; ++j) {                 // phi mask
      const int r = 4 * g + j;
      arg[j] = (r > l) ? arg[j] : ((r == l) ? 0.5f * arg[j] : 0.f);
    }
    f32x4 cam = MF(laA[b], cvt4(arg), zz);        // camTE = La@masked
    f32x4 ov = MF(ldA(chol_v_TE + off[b], l, g),
                  ldBcol(chol_amat + off[b], g, l), zz);   // LvT@La
    ov = MF(ldA(chol_v + off[b], l, g), cvt4(cam), ov);    // + Lv@camTE
    float* ob = out + off[b];
    #pragma unroll
    for (int j = 0; j < 4; ++j) ob[(4 * g + j) * 16 + l] = ov[j];
  }
}

extern "C" void kernel_launch(void* const* d_in, const int* in_sizes, int n_in,
                              void* d_out, int out_size, void* d_ws, size_t ws_size,
                              hipStream_t stream) {
  const float* mu_TE      = (const float*)d_in[0];
  const float* prec_h     = (const float*)d_in[1];
  const float* chol_v     = (const float*)d_in[2];
  const float* chol_h     = (const float*)d_in[3];
  const float* chol_hv    = (const float*)d_in[4];
  const float* chol_v_TE  = (const float*)d_in[5];
  const float* chol_h_TE  = (const float*)d_in[6];
  const float* chol_hv_TE = (const float*)d_in[7];
  const float* chol_amat  = (const float*)d_in[8];
  float* out = (float*)d_out;

  const int B = in_sizes[0] / 32;       // mu_TE is (B, 32)
  gauss_te_mf4<<<B / 16, 256, 0, stream>>>(mu_TE, prec_h, chol_v, chol_h, chol_hv,
                                           chol_v_TE, chol_h_TE, chol_hv_TE,
                                           chol_amat, out, B);
}

// Round 13
// 143.377 us; speedup vs baseline: 1.1771x; 1.1771x over previous
//
#include <hip/hip_runtime.h>

// ConvertParamsTEtoParams0TEGaussLayer — MFMA v5: zero-LDS Newton + full
// register prefetch. 64-thread blocks = 1 wave = 4 batches (round-12 showed
// multi-wave blocks spill under the VGPR cap; round-11 showed the limiter is
// per-wave MLP). All global loads are hoisted into one phase and converted to
// f16 fragments as they arrive; compute phases are the validated v3 chain.
//
// Fragment algebra (lane t = 16h + c, h=t>>4, c=t&15):
//   D-frag  reg j = D[4h+j][c]
//   B-frag  reg i = B[4h+i][c]   => B-frag(X) = cvt4(X-as-D)   (always)
//   A-frag  reg i = A[c][4h+i]   => A-frag(X^T) = cvt4(X-as-D) (always)
//                                  A-frag(X)  = cvt4(X-as-D) iff X symmetric
// Newton inverses on the matrix pipe:
//   Pinv:  X0 = 0.7*I; X <- X(2I - P X), 5 steps (rho(I-0.7P) <= ~0.3).
//   cinv:  L = I+N nilpotent: X1 = 2I-L, 3 steps exact; maintain X and X^T.
//          X1/X1^T initialized from the f16 La fragments (laB/laA) — the
//          iteration converges to inv(La_f16), same error class as the MFMA
//          products themselves.
// Chain: symS = S+S^T; M1 = Pinv@Hv; G = symS@M1; U' = Pinv@G; Z = HvT^T@M1;
// ZT = M1^T@HvT; V2 = Hv^T@U'; am = V2-Z-ZT; T1T = MF(cvt4(am), cinvA);
// arg = MF(cvt4(T1T), cinvA); phi-mask; cam = La@arg; out = LvT@La + Lv@cam.

typedef _Float16 f16x4 __attribute__((ext_vector_type(4)));
typedef float    f32x4 __attribute__((ext_vector_type(4)));

__device__ __forceinline__ unsigned int pkf(float a, float b) {
  return __builtin_bit_cast(unsigned int, __builtin_amdgcn_cvt_pkrtz(a, b));
}
__device__ __forceinline__ f16x4 mkf16x4(unsigned int lo, unsigned int hi) {
  union { unsigned int u[2]; f16x4 v; } cv; cv.u[0] = lo; cv.u[1] = hi; return cv.v;
}
__device__ __forceinline__ f16x4 cvt4(f32x4 d) {
  return mkf16x4(pkf(d[0], d[1]), pkf(d[2], d[3]));
}
__device__ __forceinline__ f16x4 cvt4f(float a, float b, float c, float d) {
  return mkf16x4(pkf(a, b), pkf(c, d));
}
__device__ __forceinline__ f32x4 MF(f16x4 a, f16x4 b, f32x4 c) {
  return __builtin_amdgcn_mfma_f32_16x16x16f16(a, b, c, 0, 0, 0);
}
// Row-pattern fragment: X[r][4h..4h+3] -> A-frag(X) (also B-frag(X^T)).
__device__ __forceinline__ f16x4 ldrow(const float* __restrict__ X, int r, int h) {
  float4 v = *reinterpret_cast<const float4*>(X + r * 16 + 4 * h);
  return cvt4f(v.x, v.y, v.z, v.w);
}
// Column-pattern fragment: X[4h+i][c] -> B-frag(X) (also A-frag(X^T)).
__device__ __forceinline__ f16x4 ldcol(const float* __restrict__ X, int h, int c) {
  const float* b = X + 4 * h * 16 + c;
  return cvt4f(b[0], b[16], b[32], b[48]);
}

__global__ __launch_bounds__(64, 4) void gauss_te_mf5(
    const float* __restrict__ mu_TE,
    const float* __restrict__ prec_h,
    const float* __restrict__ chol_v,
    const float* __restrict__ chol_h,
    const float* __restrict__ chol_hv,
    const float* __restrict__ chol_v_TE,
    const float* __restrict__ chol_h_TE,
    const float* __restrict__ chol_hv_TE,
    const float* __restrict__ chol_amat,
    float* __restrict__ out, int B)
{
  const int t = threadIdx.x;
  const int g = t >> 4;                 // h-role (row block)
  const int l = t & 15;                 // c-role (column)
  const size_t batch0 = (size_t)blockIdx.x * 4;
  const f32x4 zz = {0.f, 0.f, 0.f, 0.f};

  // ---- muv_TE passthrough (one batch per 16-lane group) ----
  out[(size_t)B * 256 + (batch0 + g) * 16 + l] = mu_TE[(batch0 + g) * 32 + l];

  size_t off[4];
  #pragma unroll
  for (int b = 0; b < 4; ++b) off[b] = (batch0 + b) * 256;

  // ---- Phase 0: prefetch ALL inputs into f16 fragments (max MLP) ----
  f16x4 lhtA[4], lhB[4], hvtA[4], hvA[4], Pf[4], laA[4], laB[4],
        lvTA[4], lvA[4], hvB[4], hvtB[4];
  #pragma unroll
  for (int b = 0; b < 4; ++b) {
    lhtA[b] = ldrow(chol_h_TE  + off[b], l, g);   // A-frag(LhT)
    lhB[b]  = ldrow(chol_h     + off[b], l, g);   // B-frag(Lh^T)
    hvtA[b] = ldrow(chol_hv_TE + off[b], l, g);   // A-frag(HvT)
    hvA[b]  = ldrow(chol_hv    + off[b], l, g);   // B-frag(Hv^T)
    Pf[b]   = ldrow(prec_h     + off[b], l, g);   // A/B-frag(P) (symmetric)
    laA[b]  = ldrow(chol_amat  + off[b], l, g);   // A-frag(La) = B-frag(La^T)
    lvTA[b] = ldrow(chol_v_TE  + off[b], l, g);   // A-frag(LvT)
    lvA[b]  = ldrow(chol_v     + off[b], l, g);   // A-frag(Lv)
    laB[b]  = ldcol(chol_amat  + off[b], g, l);   // B-frag(La)
    hvB[b]  = ldcol(chol_hv    + off[b], g, l);   // B-frag(Hv) = A-frag(Hv^T)
    hvtB[b] = ldcol(chol_hv_TE + off[b], g, l);   // B-frag(HvT) = A-frag(HvT^T)
  }

  // ---- symS = S + S^T, S = LhT@Lh^T + HvT@Hv^T (symmetric -> one frag) ----
  f16x4 syh[4];
  #pragma unroll
  for (int b = 0; b < 4; ++b) {
    f32x4 S  = MF(lhtA[b], lhB[b], zz);           // LhT @ Lh^T
    S        = MF(hvtA[b], hvA[b], S);            // + HvT @ Hv^T
    f32x4 St = MF(lhB[b], lhtA[b], zz);           // Lh @ LhT^T  (= S^T)
    St       = MF(hvA[b], hvtA[b], St);           // + Hv @ HvT^T
    syh[b] = cvt4(S + St);
  }

  // ---- Pinv by Newton (5 steps), all-MFMA, symmetric iterates ----
  f16x4 pinvF[4];
  {
    f32x4 X[4];
    #pragma unroll
    for (int b = 0; b < 4; ++b)
      #pragma unroll
      for (int j = 0; j < 4; ++j) X[b][j] = (4 * g + j == l) ? 0.7f : 0.f;
    #pragma unroll
    for (int s = 0; s < 5; ++s) {
      #pragma unroll
      for (int b = 0; b < 4; ++b) {
        f16x4 xh = cvt4(X[b]);                    // A- and B-frag of X (sym)
        f32x4 Y  = MF(Pf[b], xh, zz);             // Y = P@X
        f32x4 XY = MF(xh, cvt4(Y), zz);           // X@Y
        X[b] = 2.0f * X[b] - XY;
      }
    }
    #pragma unroll
    for (int b = 0; b < 4; ++b) pinvF[b] = cvt4(X[b]);
  }

  // ---- cinv by Newton (exact after 3 steps), maintain X and X^T ----
  // Init from the f16 La fragments: X1 = 2I - La (D-layout = laB),
  // X1^T = 2I - La^T (D-layout of transpose = laA).
  f16x4 cinvA[4];
  {
    f32x4 X[4], XT[4];
    #pragma unroll
    for (int b = 0; b < 4; ++b) {
      #pragma unroll
      for (int j = 0; j < 4; ++j) {
        const float d = (4 * g + j == l) ? 2.f : 0.f;
        X[b][j]  = d - (float)laB[b][j];          // X1   = 2I - La
        XT[b][j] = d - (float)laA[b][j];          // X1^T = 2I - La^T
      }
    }
    #pragma unroll
    for (int s = 0; s < 3; ++s) {
      #pragma unroll
      for (int b = 0; b < 4; ++b) {
        f16x4 xh  = cvt4(X[b]);                   // B-frag(X)
        f16x4 xth = cvt4(XT[b]);                  // A-frag(X) = B-frag(X^T)
        f32x4 Y   = MF(laA[b], xh, zz);           // Y = La@X
        f16x4 yh  = cvt4(Y);
        f32x4 XY  = MF(xth, yh, zz);              // X@Y
        f32x4 YT  = MF(yh, xth, zz);              // Y^T@X^T = (X@Y)^T
        X[b]  = 2.f * X[b]  - XY;
        XT[b] = 2.f * XT[b] - YT;
      }
    }
    #pragma unroll
    for (int b = 0; b < 4; ++b) cinvA[b] = cvt4(XT[b]);  // A-frag(cinv)
  }

  // ---- main chain, 4 independent batch chains ----
  #pragma unroll
  for (int b = 0; b < 4; ++b) {
    f32x4 M1 = MF(pinvF[b], hvB[b], zz);          // M1 = Pinv@Hv
    f16x4 m1h = cvt4(M1);
    f32x4 G  = MF(syh[b], m1h, zz);               // G = symS@M1 (symS as A)
    f32x4 Up = MF(pinvF[b], cvt4(G), zz);         // U' = Pinv@G = (W+W^T)@Hv
    f32x4 Z  = MF(hvtB[b], m1h, zz);              // Z   = HvT^T@M1
    f32x4 ZT = MF(m1h, hvtB[b], zz);              // Z^T = M1^T@HvT
    f32x4 V2 = MF(hvB[b], cvt4(Up), zz);          // V2' = Hv^T@U'
    f32x4 am = V2 - Z - ZT;                       // amatTE (D-layout)
    f32x4 T1T = MF(cvt4(am), cinvA[b], zz);       // (cinv@am)^T = am^T@cinv^T
    f32x4 arg = MF(cvt4(T1T), cinvA[b], zz);      // arg = cinv@am@cinv^T
    #pragma unroll
    for (int j = 0; j < 4; ++j) {                 // phi mask
      const int r = 4 * g + j;
      arg[j] = (r > l) ? arg[j] : ((r == l) ? 0.5f * arg[j] : 0.f);
    }
    f32x4 cam = MF(laA[b], cvt4(arg), zz);        // camTE = La@masked
    f32x4 ov = MF(lvTA[b], laB[b], zz);           // LvT@La
    ov = MF(lvA[b], cvt4(cam), ov);               // + Lv@camTE
    float* ob = out + off[b];
    #pragma unroll
    for (int j = 0; j < 4; ++j) ob[(4 * g + j) * 16 + l] = ov[j];
  }
}

extern "C" void kernel_launch(void* const* d_in, const int* in_sizes, int n_in,
                              void* d_out, int out_size, void* d_ws, size_t ws_size,
                              hipStream_t stream) {
  const float* mu_TE      = (const float*)d_in[0];
  const float* prec_h     = (const float*)d_in[1];
  const float* chol_v     = (const float*)d_in[2];
  const float* chol_h     = (const float*)d_in[3];
  const float* chol_hv    = (const float*)d_in[4];
  const float* chol_v_TE  = (const float*)d_in[5];
  const float* chol_h_TE  = (const float*)d_in[6];
  const float* chol_hv_TE = (const float*)d_in[7];
  const float* chol_amat  = (const float*)d_in[8];
  float* out = (float*)d_out;

  const int B = in_sizes[0] / 32;       // mu_TE is (B, 32)
  gauss_te_mf5<<<B / 4, 64, 0, stream>>>(mu_TE, prec_h, chol_v, chol_h, chol_hv,
                                         chol_v_TE, chol_h_TE, chol_hv_TE,
                                         chol_amat, out, B);
}

// Round 14
// 121.657 us; speedup vs baseline: 1.3872x; 1.1785x over previous
//
#include <hip/hip_runtime.h>

// ConvertParamsTEtoParams0TEGaussLayer — MFMA v6: zero-LDS Newton, 1 batch/wave.
// 128-thread blocks = 2 independent waves (no barriers); each wave owns ONE
// batch. Rationale (r11-r13 counters): kernel is HBM-throughput-bound at ~43%
// of achievable BW because in-flight bytes/CU (~8KB at 16 waves) < the ~9.2KB
// Little's-law requirement. One batch/wave cuts register need to ~45 VGPR so
// __launch_bounds__(128,8) (64-VGPR cap) reaches 32 waves/CU without spilling
// (r12's failure mode), doubling outstanding requests.
//
// Fragment algebra (lane t = 16h + c, h=t>>4, c=t&15):
//   D-frag  reg j = D[4h+j][c]
//   B-frag  reg i = B[4h+i][c]   => B-frag(X) = cvt4(X-as-D)   (always)
//   A-frag  reg i = A[c][4h+i]   => A-frag(X^T) = cvt4(X-as-D) (always)
//                                  A-frag(X)  = cvt4(X-as-D) iff X symmetric
// Newton inverses on the matrix pipe (validated r11/r13, absmax 0.0039):
//   Pinv:  X0 = 0.7*I; X <- X(2I - P X), 5 steps (rho(I-0.7P) <= ~0.3).
//   cinv:  L = I+N nilpotent: X1 = 2I-L (from f16 La frags), 3 steps exact;
//          maintain X and X^T together.
// Chain: symS = S+S^T; M1 = Pinv@Hv; G = symS@M1; U' = Pinv@G; Z = HvT^T@M1;
// ZT = M1^T@HvT; V2 = Hv^T@U'; am = V2-Z-ZT; T1T = MF(cvt4(am), cinvA);
// arg = MF(cvt4(T1T), cinvA); phi-mask; cam = La@arg; out = LvT@La + Lv@cam.

typedef _Float16 f16x4 __attribute__((ext_vector_type(4)));
typedef float    f32x4 __attribute__((ext_vector_type(4)));

__device__ __forceinline__ unsigned int pkf(float a, float b) {
  return __builtin_bit_cast(unsigned int, __builtin_amdgcn_cvt_pkrtz(a, b));
}
__device__ __forceinline__ f16x4 mkf16x4(unsigned int lo, unsigned int hi) {
  union { unsigned int u[2]; f16x4 v; } cv; cv.u[0] = lo; cv.u[1] = hi; return cv.v;
}
__device__ __forceinline__ f16x4 cvt4(f32x4 d) {
  return mkf16x4(pkf(d[0], d[1]), pkf(d[2], d[3]));
}
__device__ __forceinline__ f16x4 cvt4f(float a, float b, float c, float d) {
  return mkf16x4(pkf(a, b), pkf(c, d));
}
__device__ __forceinline__ f32x4 MF(f16x4 a, f16x4 b, f32x4 c) {
  return __builtin_amdgcn_mfma_f32_16x16x16f16(a, b, c, 0, 0, 0);
}
// Row-pattern fragment: X[r][4h..4h+3] -> A-frag(X) (also B-frag(X^T)).
__device__ __forceinline__ f16x4 ldrow(const float* __restrict__ X, int r, int h) {
  float4 v = *reinterpret_cast<const float4*>(X + r * 16 + 4 * h);
  return cvt4f(v.x, v.y, v.z, v.w);
}
// Column-pattern fragment: X[4h+i][c] -> B-frag(X) (also A-frag(X^T)).
__device__ __forceinline__ f16x4 ldcol(const float* __restrict__ X, int h, int c) {
  const float* b = X + 4 * h * 16 + c;
  return cvt4f(b[0], b[16], b[32], b[48]);
}

__global__ __launch_bounds__(128, 8) void gauss_te_mf6(
    const float* __restrict__ mu_TE,
    const float* __restrict__ prec_h,
    const float* __restrict__ chol_v,
    const float* __restrict__ chol_h,
    const float* __restrict__ chol_hv,
    const float* __restrict__ chol_v_TE,
    const float* __restrict__ chol_h_TE,
    const float* __restrict__ chol_hv_TE,
    const float* __restrict__ chol_amat,
    float* __restrict__ out, int B)
{
  const int w = threadIdx.x >> 6;       // wave in block (0..1), independent
  const int t = threadIdx.x & 63;       // lane in wave
  const int g = t >> 4;                 // h-role (row block)
  const int l = t & 15;                 // c-role (column)
  const size_t batch = (size_t)blockIdx.x * 2 + w;
  const size_t off = batch * 256;
  const f32x4 zz = {0.f, 0.f, 0.f, 0.f};

  // ---- muv_TE passthrough ----
  if (t < 16) out[(size_t)B * 256 + batch * 16 + t] = mu_TE[batch * 32 + t];

  // ---- symS = S + S^T, S = LhT@Lh^T + HvT@Hv^T (symmetric -> one frag) ----
  f16x4 lhtA = ldrow(chol_h_TE  + off, l, g);   // A-frag(LhT)
  f16x4 lhB  = ldrow(chol_h     + off, l, g);   // B-frag(Lh^T)
  f16x4 hvtA = ldrow(chol_hv_TE + off, l, g);   // A-frag(HvT)
  f16x4 hvA  = ldrow(chol_hv    + off, l, g);   // B-frag(Hv^T)
  f32x4 S  = MF(lhtA, lhB, zz);                 // LhT @ Lh^T
  S        = MF(hvtA, hvA, S);                  // + HvT @ Hv^T
  f32x4 St = MF(lhB, lhtA, zz);                 // Lh @ LhT^T  (= S^T)
  St       = MF(hvA, hvtA, St);                 // + Hv @ HvT^T
  f16x4 syh = cvt4(S + St);

  // ---- Pinv by Newton (5 steps), all-MFMA, symmetric iterates ----
  f16x4 pinvF;
  {
    f16x4 Pf = ldrow(prec_h + off, l, g);       // A/B-frag(P) (symmetric)
    f32x4 X;
    #pragma unroll
    for (int j = 0; j < 4; ++j) X[j] = (4 * g + j == l) ? 0.7f : 0.f;
    #pragma unroll
    for (int s = 0; s < 5; ++s) {
      f16x4 xh = cvt4(X);                       // A- and B-frag of X (sym)
      f32x4 Y  = MF(Pf, xh, zz);                // Y = P@X
      f32x4 XY = MF(xh, cvt4(Y), zz);           // X@Y
      X = 2.0f * X - XY;
    }
    pinvF = cvt4(X);
  }

  // ---- cinv by Newton (exact after 3 steps), maintain X and X^T ----
  f16x4 laA = ldrow(chol_amat + off, l, g);     // A-frag(La) = B-frag(La^T)
  f16x4 laB = ldcol(chol_amat + off, g, l);     // B-frag(La)
  f16x4 cinvA;
  {
    f32x4 X, XT;
    #pragma unroll
    for (int j = 0; j < 4; ++j) {
      const float d = (4 * g + j == l) ? 2.f : 0.f;
      X[j]  = d - (float)laB[j];                // X1   = 2I - La
      XT[j] = d - (float)laA[j];                // X1^T = 2I - La^T
    }
    #pragma unroll
    for (int s = 0; s < 3; ++s) {
      f16x4 xh  = cvt4(X);                      // B-frag(X)
      f16x4 xth = cvt4(XT);                     // A-frag(X) = B-frag(X^T)
      f32x4 Y   = MF(laA, xh, zz);              // Y = La@X
      f16x4 yh  = cvt4(Y);
      f32x4 XY  = MF(xth, yh, zz);              // X@Y
      f32x4 YT  = MF(yh, xth, zz);              // Y^T@X^T = (X@Y)^T
      X  = 2.f * X  - XY;
      XT = 2.f * XT - YT;
    }
    cinvA = cvt4(XT);                           // A-frag(cinv) = B-frag(cinv^T)
  }

  // ---- main chain ----
  f16x4 hvB  = ldcol(chol_hv    + off, g, l);   // B-frag(Hv) = A-frag(Hv^T)
  f16x4 hvtB = ldcol(chol_hv_TE + off, g, l);   // B-frag(HvT) = A-frag(HvT^T)
  f32x4 M1 = MF(pinvF, hvB, zz);                // M1 = Pinv@Hv
  f16x4 m1h = cvt4(M1);
  f32x4 G  = MF(syh, m1h, zz);                  // G = symS@M1 (symS as A)
  f32x4 Up = MF(pinvF, cvt4(G), zz);            // U' = Pinv@G = (W+W^T)@Hv
  f32x4 Z  = MF(hvtB, m1h, zz);                 // Z   = HvT^T@M1
  f32x4 ZT = MF(m1h, hvtB, zz);                 // Z^T = M1^T@HvT
  f32x4 V2 = MF(hvB, cvt4(Up), zz);             // V2' = Hv^T@U'
  f32x4 am = V2 - Z - ZT;                       // amatTE (D-layout)
  f32x4 T1T = MF(cvt4(am), cinvA, zz);          // (cinv@am)^T = am^T@cinv^T
  f32x4 arg = MF(cvt4(T1T), cinvA, zz);         // arg = cinv@am@cinv^T
  #pragma unroll
  for (int j = 0; j < 4; ++j) {                 // phi mask
    const int r = 4 * g + j;
    arg[j] = (r > l) ? arg[j] : ((r == l) ? 0.5f * arg[j] : 0.f);
  }
  f32x4 cam = MF(laA, cvt4(arg), zz);           // camTE = La@masked
  f32x4 ov = MF(ldrow(chol_v_TE + off, l, g), laB, zz);   // LvT@La
  ov = MF(ldrow(chol_v + off, l, g), cvt4(cam), ov);      // + Lv@camTE
  float* ob = out + off;
  #pragma unroll
  for (int j = 0; j < 4; ++j) ob[(4 * g + j) * 16 + l] = ov[j];
}

extern "C" void kernel_launch(void* const* d_in, const int* in_sizes, int n_in,
                              void* d_out, int out_size, void* d_ws, size_t ws_size,
                              hipStream_t stream) {
  const float* mu_TE      = (const float*)d_in[0];
  const float* prec_h     = (const float*)d_in[1];
  const float* chol_v     = (const float*)d_in[2];
  const float* chol_h     = (const float*)d_in[3];
  const float* chol_hv    = (const float*)d_in[4];
  const float* chol_v_TE  = (const float*)d_in[5];
  const float* chol_h_TE  = (const float*)d_in[6];
  const float* chol_hv_TE = (const float*)d_in[7];
  const float* chol_amat  = (const float*)d_in[8];
  float* out = (float*)d_out;

  const int B = in_sizes[0] / 32;       // mu_TE is (B, 32)
  gauss_te_mf6<<<B / 2, 128, 0, stream>>>(mu_TE, prec_h, chol_v, chol_h, chol_hv,
                                          chol_v_TE, chol_h_TE, chol_hv_TE,
                                          chol_amat, out, B);
}

// Round 15
// 117.459 us; speedup vs baseline: 1.4368x; 1.0357x over previous
//
#include <hip/hip_runtime.h>

// ConvertParamsTEtoParams0TEGaussLayer — MFMA v7: zero-LDS Newton,
// 1 batch/wave, duplicate global reads replaced by in-register transposes.
// r9/r11/r14 all plateau at ~122us across wave-count configs => the wall is
// aggregate vector-memory traffic (~720MB at 5.9 TB/s ~ 94% of the 6.3 TB/s
// copy ceiling), not HBM, not occupancy. This version cuts VMEM bytes:
//   - B-frags of Hv/HvT/La are derived from their A-frags via ds_bpermute
//     lane transposes (idle LDS pipe) instead of 3 extra 1KB column reads.
//   - __launch_bounds__(128,4) removes r14's spill (VGPR budget 128).
//
// Fragment algebra (lane t = 16h + c, h=t>>4, c=t&15):
//   D-frag  reg j = D[4h+j][c]
//   B-frag  reg i = B[4h+i][c]   => B-frag(X) = cvt4(X-as-D)   (always)
//   A-frag  reg i = A[c][4h+i]   => A-frag(X^T) = cvt4(X-as-D) (always)
//                                  A-frag(X)  = cvt4(X-as-D) iff X symmetric
// In-register transpose: B-frag(X) lane(h,c) elem i = A-frag(X) lane
//   L+i (L = 16*(c>>2)+4h), elem (c&3)  -> 8 bpermute + selects per matrix.
// Newton inverses (validated r11-r14, absmax 0.0039):
//   Pinv: X0=0.7I; X <- X(2I-PX), 5 steps. cinv: X1=2I-L, 3 steps exact.
// Chain: symS = S+S^T; M1 = Pinv@Hv; G = symS@M1; U' = Pinv@G; Z = HvT^T@M1;
// ZT = M1^T@HvT; V2 = Hv^T@U'; am = V2-Z-ZT; T1T = MF(cvt4(am), cinvA);
// arg = MF(cvt4(T1T), cinvA); phi-mask; cam = La@arg; out = LvT@La + Lv@cam.

typedef _Float16 f16x4 __attribute__((ext_vector_type(4)));
typedef float    f32x4 __attribute__((ext_vector_type(4)));

__device__ __forceinline__ unsigned int pkf(float a, float b) {
  return __builtin_bit_cast(unsigned int, __builtin_amdgcn_cvt_pkrtz(a, b));
}
__device__ __forceinline__ f16x4 mkf16x4(unsigned int lo, unsigned int hi) {
  union { unsigned int u[2]; f16x4 v; } cv; cv.u[0] = lo; cv.u[1] = hi; return cv.v;
}
__device__ __forceinline__ f16x4 cvt4(f32x4 d) {
  return mkf16x4(pkf(d[0], d[1]), pkf(d[2], d[3]));
}
__device__ __forceinline__ f16x4 cvt4f(float a, float b, float c, float d) {
  return mkf16x4(pkf(a, b), pkf(c, d));
}
__device__ __forceinline__ f32x4 MF(f16x4 a, f16x4 b, f32x4 c) {
  return __builtin_amdgcn_mfma_f32_16x16x16f16(a, b, c, 0, 0, 0);
}
// Row-pattern fragment: X[r][4h..4h+3] -> A-frag(X) (also B-frag(X^T)).
__device__ __forceinline__ f16x4 ldrow(const float* __restrict__ X, int r, int h) {
  float4 v = *reinterpret_cast<const float4*>(X + r * 16 + 4 * h);
  return cvt4f(v.x, v.y, v.z, v.w);
}
// B-frag(X) from A-frag(X) via lane transpose (no global traffic).
// dest lane (h,c) elem i = src lane L+i (L=16*(c>>2)+4h), elem (c&3).
__device__ __forceinline__ f16x4 tfrag(f16x4 a, int h, int c) {
  union { f16x4 v; unsigned int u[2]; } s; s.v = a;
  const int L4 = 4 * (16 * (c >> 2) + 4 * h);      // byte addr of lane L
  unsigned int t00 = __builtin_amdgcn_ds_bpermute(L4,      (int)s.u[0]);
  unsigned int t01 = __builtin_amdgcn_ds_bpermute(L4 + 4,  (int)s.u[0]);
  unsigned int t02 = __builtin_amdgcn_ds_bpermute(L4 + 8,  (int)s.u[0]);
  unsigned int t03 = __builtin_amdgcn_ds_bpermute(L4 + 12, (int)s.u[0]);
  unsigned int t10 = __builtin_amdgcn_ds_bpermute(L4,      (int)s.u[1]);
  unsigned int t11 = __builtin_amdgcn_ds_bpermute(L4 + 4,  (int)s.u[1]);
  unsigned int t12 = __builtin_amdgcn_ds_bpermute(L4 + 8,  (int)s.u[1]);
  unsigned int t13 = __builtin_amdgcn_ds_bpermute(L4 + 12, (int)s.u[1]);
  const bool wsel = (c & 2) != 0;                  // src word = (c&3)>>1
  unsigned int u0 = wsel ? t10 : t00;
  unsigned int u1 = wsel ? t11 : t01;
  unsigned int u2 = wsel ? t12 : t02;
  unsigned int u3 = wsel ? t13 : t03;
  // pick half (c&1) of each word: same selector family as the verified ldsA.
  unsigned int sel = 0x05040100u + ((c & 1) ? 0x02020202u : 0u);
  return mkf16x4(__builtin_amdgcn_perm(u1, u0, sel),
                 __builtin_amdgcn_perm(u3, u2, sel));
}

__global__ __launch_bounds__(128, 4) void gauss_te_mf7(
    const float* __restrict__ mu_TE,
    const float* __restrict__ prec_h,
    const float* __restrict__ chol_v,
    const float* __restrict__ chol_h,
    const float* __restrict__ chol_hv,
    const float* __restrict__ chol_v_TE,
    const float* __restrict__ chol_h_TE,
    const float* __restrict__ chol_hv_TE,
    const float* __restrict__ chol_amat,
    float* __restrict__ out, int B)
{
  const int w = threadIdx.x >> 6;       // wave in block (0..1), independent
  const int t = threadIdx.x & 63;       // lane in wave
  const int g = t >> 4;                 // h-role (row block)
  const int l = t & 15;                 // c-role (column)
  const size_t batch = (size_t)blockIdx.x * 2 + w;
  const size_t off = batch * 256;
  const f32x4 zz = {0.f, 0.f, 0.f, 0.f};

  // ---- muv_TE passthrough ----
  if (t < 16) out[(size_t)B * 256 + batch * 16 + t] = mu_TE[batch * 32 + t];

  // ---- symS = S + S^T, S = LhT@Lh^T + HvT@Hv^T (symmetric -> one frag) ----
  f16x4 lhtA = ldrow(chol_h_TE  + off, l, g);   // A-frag(LhT)
  f16x4 lhB  = ldrow(chol_h     + off, l, g);   // B-frag(Lh^T) = A-frag(Lh)
  f16x4 hvtA = ldrow(chol_hv_TE + off, l, g);   // A-frag(HvT)
  f16x4 hvA  = ldrow(chol_hv    + off, l, g);   // A-frag(Hv) = B-frag(Hv^T)
  f32x4 S  = MF(lhtA, lhB, zz);                 // LhT @ Lh^T
  S        = MF(hvtA, hvA, S);                  // + HvT @ Hv^T
  f32x4 St = MF(lhB, lhtA, zz);                 // Lh @ LhT^T  (= S^T)
  St       = MF(hvA, hvtA, St);                 // + Hv @ HvT^T
  f16x4 syh = cvt4(S + St);

  // ---- B-frags via in-register lane transpose (no extra global reads) ----
  f16x4 hvB  = tfrag(hvA,  g, l);               // B-frag(Hv) = A-frag(Hv^T)
  f16x4 hvtB = tfrag(hvtA, g, l);               // B-frag(HvT) = A-frag(HvT^T)

  // ---- Pinv by Newton (5 steps), all-MFMA, symmetric iterates ----
  f16x4 pinvF;
  {
    f16x4 Pf = ldrow(prec_h + off, l, g);       // A/B-frag(P) (symmetric)
    f32x4 X;
    #pragma unroll
    for (int j = 0; j < 4; ++j) X[j] = (4 * g + j == l) ? 0.7f : 0.f;
    #pragma unroll
    for (int s = 0; s < 5; ++s) {
      f16x4 xh = cvt4(X);                       // A- and B-frag of X (sym)
      f32x4 Y  = MF(Pf, xh, zz);                // Y = P@X
      f32x4 XY = MF(xh, cvt4(Y), zz);           // X@Y
      X = 2.0f * X - XY;
    }
    pinvF = cvt4(X);
  }

  // ---- cinv by Newton (exact after 3 steps), maintain X and X^T ----
  f16x4 laA = ldrow(chol_amat + off, l, g);     // A-frag(La) = B-frag(La^T)
  f16x4 laB = tfrag(laA, g, l);                 // B-frag(La)
  f16x4 cinvA;
  {
    f32x4 X, XT;
    #pragma unroll
    for (int j = 0; j < 4; ++j) {
      const float d = (4 * g + j == l) ? 2.f : 0.f;
      X[j]  = d - (float)laB[j];                // X1   = 2I - La
      XT[j] = d - (float)laA[j];                // X1^T = 2I - La^T
    }
    #pragma unroll
    for (int s = 0; s < 3; ++s) {
      f16x4 xh  = cvt4(X);                      // B-frag(X)
      f16x4 xth = cvt4(XT);                     // A-frag(X) = B-frag(X^T)
      f32x4 Y   = MF(laA, xh, zz);              // Y = La@X
      f16x4 yh  = cvt4(Y);
      f32x4 XY  = MF(xth, yh, zz);              // X@Y
      f32x4 YT  = MF(yh, xth, zz);              // Y^T@X^T = (X@Y)^T
      X  = 2.f * X  - XY;
      XT = 2.f * XT - YT;
    }
    cinvA = cvt4(XT);                           // A-frag(cinv) = B-frag(cinv^T)
  }

  // ---- main chain ----
  f32x4 M1 = MF(pinvF, hvB, zz);                // M1 = Pinv@Hv
  f16x4 m1h = cvt4(M1);
  f32x4 G  = MF(syh, m1h, zz);                  // G = symS@M1 (symS as A)
  f32x4 Up = MF(pinvF, cvt4(G), zz);            // U' = Pinv@G = (W+W^T)@Hv
  f32x4 Z  = MF(hvtB, m1h, zz);                 // Z   = HvT^T@M1
  f32x4 ZT = MF(m1h, hvtB, zz);                 // Z^T = M1^T@HvT
  f32x4 V2 = MF(hvB, cvt4(Up), zz);             // V2' = Hv^T@U'
  f32x4 am = V2 - Z - ZT;                       // amatTE (D-layout)
  f32x4 T1T = MF(cvt4(am), cinvA, zz);          // (cinv@am)^T = am^T@cinv^T
  f32x4 arg = MF(cvt4(T1T), cinvA, zz);         // arg = cinv@am@cinv^T
  #pragma unroll
  for (int j = 0; j < 4; ++j) {                 // phi mask
    const int r = 4 * g + j;
    arg[j] = (r > l) ? arg[j] : ((r == l) ? 0.5f * arg[j] : 0.f);
  }
  f32x4 cam = MF(laA, cvt4(arg), zz);           // camTE = La@masked
  f32x4 ov = MF(ldrow(chol_v_TE + off, l, g), laB, zz);   // LvT@La
  ov = MF(ldrow(chol_v + off, l, g), cvt4(cam), ov);      // + Lv@camTE
  float* ob = out + off;
  #pragma unroll
  for (int j = 0; j < 4; ++j) ob[(4 * g + j) * 16 + l] = ov[j];
}

extern "C" void kernel_launch(void* const* d_in, const int* in_sizes, int n_in,
                              void* d_out, int out_size, void* d_ws, size_t ws_size,
                              hipStream_t stream) {
  const float* mu_TE      = (const float*)d_in[0];
  const float* prec_h     = (const float*)d_in[1];
  const float* chol_v     = (const float*)d_in[2];
  const float* chol_h     = (const float*)d_in[3];
  const float* chol_hv    = (const float*)d_in[4];
  const float* chol_v_TE  = (const float*)d_in[5];
  const float* chol_h_TE  = (const float*)d_in[6];
  const float* chol_hv_TE = (const float*)d_in[7];
  const float* chol_amat  = (const float*)d_in[8];
  float* out = (float*)d_out;

  const int B = in_sizes[0] / 32;       // mu_TE is (B, 32)
  gauss_te_mf7<<<B / 2, 128, 0, stream>>>(mu_TE, prec_h, chol_v, chol_h, chol_hv,
                                          chol_v_TE, chol_h_TE, chol_hv_TE,
                                          chol_amat, out, B);
}

// Round 16
// 115.412 us; speedup vs baseline: 1.4623x; 1.0177x over previous
//
#include <hip/hip_runtime.h>

// ConvertParamsTEtoParams0TEGaussLayer — MFMA v8: v7 + grouped raw-f32 loads.
// All 8 row-pattern float4 loads are issued back-to-back and pinned live with
// an empty asm keep-alive BEFORE any f16 conversion, forcing 8 outstanding
// 1KB loads per wave (r15 compiled to VGPR=32 => ~1.5 in flight). Everything
// else is the validated v7 structure: zero-LDS Newton inverses, in-register
// lane transposes for B-frags, 1 batch/wave, 2-wave blocks.
//
// Fragment algebra (lane t = 16h + c, h=t>>4, c=t&15):
//   D-frag  reg j = D[4h+j][c]
//   B-frag  reg i = B[4h+i][c]   => B-frag(X) = cvt4(X-as-D)   (always)
//   A-frag  reg i = A[c][4h+i]   => A-frag(X^T) = cvt4(X-as-D) (always)
//                                  A-frag(X)  = cvt4(X-as-D) iff X symmetric
// In-register transpose tfrag: B-frag(X) from A-frag(X) via 8 ds_bpermute.
// Newton inverses (validated r11-r15, absmax 0.0039):
//   Pinv: X0=0.7I; X <- X(2I-PX), 5 steps. cinv: X1=2I-L, 3 steps exact.
// Chain: symS = S+S^T; M1 = Pinv@Hv; G = symS@M1; U' = Pinv@G; Z = HvT^T@M1;
// ZT = M1^T@HvT; V2 = Hv^T@U'; am = V2-Z-ZT; T1T = MF(cvt4(am), cinvA);
// arg = MF(cvt4(T1T), cinvA); phi-mask; cam = La@arg; out = LvT@La + Lv@cam.

typedef _Float16 f16x4 __attribute__((ext_vector_type(4)));
typedef float    f32x4 __attribute__((ext_vector_type(4)));

__device__ __forceinline__ unsigned int pkf(float a, float b) {
  return __builtin_bit_cast(unsigned int, __builtin_amdgcn_cvt_pkrtz(a, b));
}
__device__ __forceinline__ f16x4 mkf16x4(unsigned int lo, unsigned int hi) {
  union { unsigned int u[2]; f16x4 v; } cv; cv.u[0] = lo; cv.u[1] = hi; return cv.v;
}
__device__ __forceinline__ f16x4 cvt4(f32x4 d) {
  return mkf16x4(pkf(d[0], d[1]), pkf(d[2], d[3]));
}
__device__ __forceinline__ f16x4 cvt4q(float4 v) {
  return mkf16x4(pkf(v.x, v.y), pkf(v.z, v.w));
}
__device__ __forceinline__ f32x4 MF(f16x4 a, f16x4 b, f32x4 c) {
  return __builtin_amdgcn_mfma_f32_16x16x16f16(a, b, c, 0, 0, 0);
}
// B-frag(X) from A-frag(X) via lane transpose (no global traffic).
// dest lane (h,c) elem i = src lane L+i (L=16*(c>>2)+4h), elem (c&3).
__device__ __forceinline__ f16x4 tfrag(f16x4 a, int h, int c) {
  union { f16x4 v; unsigned int u[2]; } s; s.v = a;
  const int L4 = 4 * (16 * (c >> 2) + 4 * h);      // byte addr of lane L
  unsigned int t00 = __builtin_amdgcn_ds_bpermute(L4,      (int)s.u[0]);
  unsigned int t01 = __builtin_amdgcn_ds_bpermute(L4 + 4,  (int)s.u[0]);
  unsigned int t02 = __builtin_amdgcn_ds_bpermute(L4 + 8,  (int)s.u[0]);
  unsigned int t03 = __builtin_amdgcn_ds_bpermute(L4 + 12, (int)s.u[0]);
  unsigned int t10 = __builtin_amdgcn_ds_bpermute(L4,      (int)s.u[1]);
  unsigned int t11 = __builtin_amdgcn_ds_bpermute(L4 + 4,  (int)s.u[1]);
  unsigned int t12 = __builtin_amdgcn_ds_bpermute(L4 + 8,  (int)s.u[1]);
  unsigned int t13 = __builtin_amdgcn_ds_bpermute(L4 + 12, (int)s.u[1]);
  const bool wsel = (c & 2) != 0;                  // src word = (c&3)>>1
  unsigned int u0 = wsel ? t10 : t00;
  unsigned int u1 = wsel ? t11 : t01;
  unsigned int u2 = wsel ? t12 : t02;
  unsigned int u3 = wsel ? t13 : t03;
  unsigned int sel = 0x05040100u + ((c & 1) ? 0x02020202u : 0u);
  return mkf16x4(__builtin_amdgcn_perm(u1, u0, sel),
                 __builtin_amdgcn_perm(u3, u2, sel));
}

#define KEEP4(v) asm volatile("" : "+v"(v.x), "+v"(v.y), "+v"(v.z), "+v"(v.w))

__global__ __launch_bounds__(128, 4) void gauss_te_mf8(
    const float* __restrict__ mu_TE,
    const float* __restrict__ prec_h,
    const float* __restrict__ chol_v,
    const float* __restrict__ chol_h,
    const float* __restrict__ chol_hv,
    const float* __restrict__ chol_v_TE,
    const float* __restrict__ chol_h_TE,
    const float* __restrict__ chol_hv_TE,
    const float* __restrict__ chol_amat,
    float* __restrict__ out, int B)
{
  const int w = threadIdx.x >> 6;       // wave in block (0..1), independent
  const int t = threadIdx.x & 63;       // lane in wave
  const int g = t >> 4;                 // h-role (row block)
  const int l = t & 15;                 // c-role (column)
  const size_t batch = (size_t)blockIdx.x * 2 + w;
  const size_t off = batch * 256;
  const size_t ro = off + (size_t)l * 16 + 4 * g;  // row-pattern element offset
  const f32x4 zz = {0.f, 0.f, 0.f, 0.f};

  // ---- Phase 0: issue ALL global reads back-to-back, pin live, then cvt ----
  float4 rLhT = *reinterpret_cast<const float4*>(chol_h_TE  + ro);
  float4 rLh  = *reinterpret_cast<const float4*>(chol_h     + ro);
  float4 rHvT = *reinterpret_cast<const float4*>(chol_hv_TE + ro);
  float4 rHv  = *reinterpret_cast<const float4*>(chol_hv    + ro);
  float4 rP   = *reinterpret_cast<const float4*>(prec_h     + ro);
  float4 rLa  = *reinterpret_cast<const float4*>(chol_amat  + ro);
  float4 rLvT = *reinterpret_cast<const float4*>(chol_v_TE  + ro);
  float4 rLv  = *reinterpret_cast<const float4*>(chol_v     + ro);
  float mu = (t < 16) ? mu_TE[batch * 32 + t] : 0.f;
  KEEP4(rLhT); KEEP4(rLh); KEEP4(rHvT); KEEP4(rHv);
  KEEP4(rP);   KEEP4(rLa); KEEP4(rLvT); KEEP4(rLv);

  // ---- muv_TE passthrough ----
  if (t < 16) out[(size_t)B * 256 + batch * 16 + t] = mu;

  f16x4 lhtA = cvt4q(rLhT);             // A-frag(LhT)
  f16x4 lhB  = cvt4q(rLh);              // B-frag(Lh^T) = A-frag(Lh)
  f16x4 hvtA = cvt4q(rHvT);             // A-frag(HvT)
  f16x4 hvA  = cvt4q(rHv);              // A-frag(Hv) = B-frag(Hv^T)
  f16x4 Pf   = cvt4q(rP);               // A/B-frag(P) (symmetric)
  f16x4 laA  = cvt4q(rLa);              // A-frag(La) = B-frag(La^T)
  f16x4 lvTA = cvt4q(rLvT);             // A-frag(LvT)
  f16x4 lvA  = cvt4q(rLv);              // A-frag(Lv)

  // ---- symS = S + S^T, S = LhT@Lh^T + HvT@Hv^T (symmetric -> one frag) ----
  f32x4 S  = MF(lhtA, lhB, zz);                 // LhT @ Lh^T
  S        = MF(hvtA, hvA, S);                  // + HvT @ Hv^T
  f32x4 St = MF(lhB, lhtA, zz);                 // Lh @ LhT^T  (= S^T)
  St       = MF(hvA, hvtA, St);                 // + Hv @ HvT^T
  f16x4 syh = cvt4(S + St);

  // ---- B-frags via in-register lane transpose (no extra global reads) ----
  f16x4 hvB  = tfrag(hvA,  g, l);               // B-frag(Hv) = A-frag(Hv^T)
  f16x4 hvtB = tfrag(hvtA, g, l);               // B-frag(HvT) = A-frag(HvT^T)
  f16x4 laB  = tfrag(laA,  g, l);               // B-frag(La)

  // ---- Pinv by Newton (5 steps), all-MFMA, symmetric iterates ----
  f16x4 pinvF;
  {
    f32x4 X;
    #pragma unroll
    for (int j = 0; j < 4; ++j) X[j] = (4 * g + j == l) ? 0.7f : 0.f;
    #pragma unroll
    for (int s = 0; s < 5; ++s) {
      f16x4 xh = cvt4(X);                       // A- and B-frag of X (sym)
      f32x4 Y  = MF(Pf, xh, zz);                // Y = P@X
      f32x4 XY = MF(xh, cvt4(Y), zz);           // X@Y
      X = 2.0f * X - XY;
    }
    pinvF = cvt4(X);
  }

  // ---- cinv by Newton (exact after 3 steps), maintain X and X^T ----
  f16x4 cinvA;
  {
    f32x4 X, XT;
    #pragma unroll
    for (int j = 0; j < 4; ++j) {
      const float d = (4 * g + j == l) ? 2.f : 0.f;
      X[j]  = d - (float)laB[j];                // X1   = 2I - La
      XT[j] = d - (float)laA[j];                // X1^T = 2I - La^T
    }
    #pragma unroll
    for (int s = 0; s < 3; ++s) {
      f16x4 xh  = cvt4(X);                      // B-frag(X)
      f16x4 xth = cvt4(XT);                     // A-frag(X) = B-frag(X^T)
      f32x4 Y   = MF(laA, xh, zz);              // Y = La@X
      f16x4 yh  = cvt4(Y);
      f32x4 XY  = MF(xth, yh, zz);              // X@Y
      f32x4 YT  = MF(yh, xth, zz);              // Y^T@X^T = (X@Y)^T
      X  = 2.f * X  - XY;
      XT = 2.f * XT - YT;
    }
    cinvA = cvt4(XT);                           // A-frag(cinv) = B-frag(cinv^T)
  }

  // ---- main chain ----
  f32x4 M1 = MF(pinvF, hvB, zz);                // M1 = Pinv@Hv
  f16x4 m1h = cvt4(M1);
  f32x4 G  = MF(syh, m1h, zz);                  // G = symS@M1 (symS as A)
  f32x4 Up = MF(pinvF, cvt4(G), zz);            // U' = Pinv@G = (W+W^T)@Hv
  f32x4 Z  = MF(hvtB, m1h, zz);                 // Z   = HvT^T@M1
  f32x4 ZT = MF(m1h, hvtB, zz);                 // Z^T = M1^T@HvT
  f32x4 V2 = MF(hvB, cvt4(Up), zz);             // V2' = Hv^T@U'
  f32x4 am = V2 - Z - ZT;                       // amatTE (D-layout)
  f32x4 T1T = MF(cvt4(am), cinvA, zz);          // (cinv@am)^T = am^T@cinv^T
  f32x4 arg = MF(cvt4(T1T), cinvA, zz);         // arg = cinv@am@cinv^T
  #pragma unroll
  for (int j = 0; j < 4; ++j) {                 // phi mask
    const int r = 4 * g + j;
    arg[j] = (r > l) ? arg[j] : ((r == l) ? 0.5f * arg[j] : 0.f);
  }
  f32x4 cam = MF(laA, cvt4(arg), zz);           // camTE = La@masked
  f32x4 ov = MF(lvTA, laB, zz);                 // LvT@La
  ov = MF(lvA, cvt4(cam), ov);                  // + Lv@camTE
  float* ob = out + off;
  #pragma unroll
  for (int j = 0; j < 4; ++j) ob[(4 * g + j) * 16 + l] = ov[j];
}

extern "C" void kernel_launch(void* const* d_in, const int* in_sizes, int n_in,
                              void* d_out, int out_size, void* d_ws, size_t ws_size,
                              hipStream_t stream) {
  const float* mu_TE      = (const float*)d_in[0];
  const float* prec_h     = (const float*)d_in[1];
  const float* chol_v     = (const float*)d_in[2];
  const float* chol_h     = (const float*)d_in[3];
  const float* chol_hv    = (const float*)d_in[4];
  const float* chol_v_TE  = (const float*)d_in[5];
  const float* chol_h_TE  = (const float*)d_in[6];
  const float* chol_hv_TE = (const float*)d_in[7];
  const float* chol_amat  = (const float*)d_in[8];
  float* out = (float*)d_out;

  const int B = in_sizes[0] / 32;       // mu_TE is (B, 32)
  gauss_te_mf8<<<B / 2, 128, 0, stream>>>(mu_TE, prec_h, chol_v, chol_h, chol_hv,
                                          chol_v_TE, chol_h_TE, chol_hv_TE,
                                          chol_amat, out, B);
}